// Round 6
// baseline (418.870 us; speedup 1.0000x reference)
//
#include <hip/hip_runtime.h>
#include <hip/hip_bf16.h>
#include <math.h>

// CFConv: out[a][f] = sum_n x[nbr[a][n]][f] * W[a][n][f]
//   W = (softplus(rbf @ w1 + b1)) @ w2 + b2
// N=20000 atoms, NB=32 neighbors, F=128, RBF=64.
//
// R6 = R5 + two VALU/latency cuts (R5 counters: VALUBusy 62% dominant,
// MfmaUtil 11%, HBM 22% -> VALU-bound, softplus is ~half the VALU time):
//  (1) scale folding: w1,b1 pre-multiplied by log2e; w2 by ln2. softplus
//      collapses to log2(1+exp2(acc)) = v_exp_f32 + v_add + v_log_f32
//      (3 instrs, ~18cyc vs ~28cyc for the max/fabs/mul/log/exp form).
//      Safe: acc = h*log2e with |h|<~10 -> exp2 in range; monotone, no
//      cancellation; error << bf16 rounding of H.
//  (2) x-row prefetch: the 16 neighbor rows of the half are loaded into
//      registers BEFORE GEMM1 (addresses known at half start), hiding
//      ~300cyc gather latency behind ~2000cyc of MFMA+softplus.
// Structure unchanged from R5: 80 KB LDS (2 blocks/CU), 8 waves/block, one
// atom per wave in two 16-row halves, swizzled wave-private LDS band for
// H then W, coalesced 512B x reads, LDS_FENCE ordering (R4's TBAA bug).

#define NB     32
#define FD     128
#define RD     64
#define WAVES  8
#define NTILES 2500   // 20000 / 8

#define LOG2E 1.4426950408889634f
#define LN2   0.6931471805599453f

typedef short  short8  __attribute__((ext_vector_type(8)));
typedef float  floatx4 __attribute__((ext_vector_type(4)));
typedef float  floatx2 __attribute__((ext_vector_type(2)));

#define LDS_FENCE() asm volatile("" ::: "memory")  // compiler-only ordering, no instr

static __device__ __forceinline__ unsigned pk2(float a, float b) {
  // packed fp32->bf16 RNE (v_cvt_pk_bf16_f32 on gfx950); low 16 = a
  __hip_bfloat162 h = __float22bfloat162_rn(float2{a, b});
  unsigned u;
  __builtin_memcpy(&u, &h, sizeof(u));
  return u;
}

// log2-domain softplus: caller folded log2e into the GEMM1 operands and ln2
// into the GEMM2 weights. 2 transcendentals + 1 add, no abs/max/muls.
static __device__ __forceinline__ float sp2(float acc) {
  return __builtin_amdgcn_logf(1.0f + __builtin_amdgcn_exp2f(acc));
}

__global__ __launch_bounds__(512, 4)  // 4 waves/EU = 2 blocks/CU (<=128 regs/wave)
void cfconv_kernel(const float* __restrict__ x,
                   const float* __restrict__ rbf,
                   const int*   __restrict__ nbr,
                   const float* __restrict__ w1,
                   const float* __restrict__ b1,
                   const float* __restrict__ w2,
                   const float* __restrict__ b2,
                   float* __restrict__ out) {
  // B-fragment layout: frag[kt*8+nt][lane][j] = B[kt*32 + (lane>>4)*8 + j][nt*16 + (lane&15)]
  __shared__ __align__(16) short w1f[16][64][8];        // 16 KB
  __shared__ __align__(16) short w2f[32][64][8];        // 32 KB
  // per-wave 16-row x 128-col bf16 staging (H, then W); 16B-block XOR swizzle:
  // element (row, col) lives at band[row][ ((col>>3 ^ row)&15)*8 + (col&7) ]
  __shared__ __align__(16) short hbuf[WAVES * 16][128]; // 32 KB -> total exactly 80 KB

  const int tid  = threadIdx.x;
  const int lane = tid & 63;
  const int wv   = tid >> 6;
  const int q    = lane >> 4;   // k-quad (A/B) or row-quad (C)
  const int ln   = lane & 15;   // m (A/C row) or n (B/C col) inside a 16-tile

  // ---- prepack weights (with scale folding) -> bf16 B-frags in LDS ----
  for (int i = tid; i < RD * FD; i += 512) {
    int k = i >> 7, n = i & 127, kk = k & 31;
    w1f[(k >> 5) * 8 + (n >> 4)][(kk >> 3) * 16 + (n & 15)][kk & 7] =
        (short)pk2(w1[i] * LOG2E, 0.f);
  }
  for (int i = tid; i < FD * FD; i += 512) {
    int k = i >> 7, n = i & 127, kk = k & 31;
    w2f[(k >> 5) * 8 + (n >> 4)][(kk >> 3) * 16 + (n & 15)][kk & 7] =
        (short)pk2(w2[i] * LN2, 0.f);
  }
  float b1v[8], b2v[8];
#pragma unroll
  for (int nt = 0; nt < 8; ++nt) {
    b1v[nt] = b1[nt * 16 + ln] * LOG2E;
    b2v[nt] = b2[nt * 16 + ln];
  }
  __syncthreads();  // the only barrier; hbuf use below is wave-private

  short (*band)[128] = &hbuf[wv * 16];
  const int cb2 = (lane * 2) >> 3;   // epilogue col-block for f = {2*lane, 2*lane+1}
  const int cl2 = (lane * 2) & 7;

  for (int tile = blockIdx.x; tile < NTILES; tile += gridDim.x) {
    const int atom = tile * WAVES + wv;
    const int prow = atom * NB;
    const int* nbp = nbr + prow;

    float o0 = 0.f, o1 = 0.f;

#pragma unroll
    for (int mt = 0; mt < 2; ++mt) {
      // ---- rbf A-frags for this 16-row half (nontemporal: streamed once) ----
      const float* src = rbf + (prow + mt * 16 + ln) * RD + q * 8;
      short8 afrag[2];
#pragma unroll
      for (int kt = 0; kt < 2; ++kt) {
        floatx4 lo = __builtin_nontemporal_load((const floatx4*)(src + kt * 32));
        floatx4 hi = __builtin_nontemporal_load((const floatx4*)(src + kt * 32 + 4));
        union { short8 s8; unsigned u[4]; } f;
        f.u[0] = pk2(lo[0], lo[1]);
        f.u[1] = pk2(lo[2], lo[3]);
        f.u[2] = pk2(hi[0], hi[1]);
        f.u[3] = pk2(hi[2], hi[3]);
        afrag[kt] = f.s8;
      }

      // ---- x-row prefetch for the epilogue (issue BEFORE the GEMMs) ----
      floatx2 xpre[16];
#pragma unroll
      for (int r = 0; r < 16; ++r) {
        const int j = nbp[mt * 16 + r];   // wave-uniform -> s_load
        xpre[r] = *(const floatx2*)(x + j * FD + lane * 2);
      }

      // ---- GEMM1: acc = (rbf @ w1 + b1) * log2e (scales folded), K=64 ----
      floatx4 acc[8];
#pragma unroll
      for (int nt = 0; nt < 8; ++nt) acc[nt] = floatx4{0.f, 0.f, 0.f, 0.f};
#pragma unroll
      for (int kt = 0; kt < 2; ++kt)
#pragma unroll
        for (int nt = 0; nt < 8; ++nt) {
          short8 bfrag = *(const short8*)&w1f[kt * 8 + nt][lane][0];
          acc[nt] = __builtin_amdgcn_mfma_f32_16x16x32_bf16(
              afrag[kt], bfrag, acc[nt], 0, 0, 0);
        }

      // ---- H' = log2(1+2^acc) -> bf16 -> swizzled band (C-layout) ----
#pragma unroll
      for (int nt = 0; nt < 8; ++nt) {
        const int c  = nt * 16 + ln;
        const int cb = c >> 3, cl = c & 7;
        unsigned u01 = pk2(sp2(acc[nt][0] + b1v[nt]), sp2(acc[nt][1] + b1v[nt]));
        unsigned u23 = pk2(sp2(acc[nt][2] + b1v[nt]), sp2(acc[nt][3] + b1v[nt]));
        band[q * 4 + 0][(((cb ^ (q * 4 + 0)) & 15) << 3) | cl] = (short)u01;
        band[q * 4 + 1][(((cb ^ (q * 4 + 1)) & 15) << 3) | cl] = (short)(u01 >> 16);
        band[q * 4 + 2][(((cb ^ (q * 4 + 2)) & 15) << 3) | cl] = (short)u23;
        band[q * 4 + 3][(((cb ^ (q * 4 + 3)) & 15) << 3) | cl] = (short)(u23 >> 16);
      }
      LDS_FENCE();  // H writes must precede hfrag reads in program order

      // ---- H A-frags from band: row=ln, cols kt*32+q*8..+7 (b128, swizzled) ----
      short8 hfrag[4];
#pragma unroll
      for (int kt = 0; kt < 4; ++kt) {
        const int pb = ((kt * 4 + q) ^ ln) & 15;
        hfrag[kt] = *(const short8*)&band[ln][pb << 3];
      }
      LDS_FENCE();  // hfrag reads must precede W overwrite

      // ---- GEMM2: W = H' @ (ln2*w2) + b2, K=128 (reuse acc) ----
#pragma unroll
      for (int nt = 0; nt < 8; ++nt) acc[nt] = floatx4{0.f, 0.f, 0.f, 0.f};
#pragma unroll
      for (int kt = 0; kt < 4; ++kt)
#pragma unroll
        for (int nt = 0; nt < 8; ++nt) {
          short8 bfrag = *(const short8*)&w2f[kt * 8 + nt][lane][0];
          acc[nt] = __builtin_amdgcn_mfma_f32_16x16x32_bf16(
              hfrag[kt], bfrag, acc[nt], 0, 0, 0);
        }

      // ---- W (bf16) back into the same band ----
#pragma unroll
      for (int nt = 0; nt < 8; ++nt) {
        const int c  = nt * 16 + ln;
        const int cb = c >> 3, cl = c & 7;
        unsigned u01 = pk2(acc[nt][0] + b2v[nt], acc[nt][1] + b2v[nt]);
        unsigned u23 = pk2(acc[nt][2] + b2v[nt], acc[nt][3] + b2v[nt]);
        band[q * 4 + 0][(((cb ^ (q * 4 + 0)) & 15) << 3) | cl] = (short)u01;
        band[q * 4 + 1][(((cb ^ (q * 4 + 1)) & 15) << 3) | cl] = (short)(u01 >> 16);
        band[q * 4 + 2][(((cb ^ (q * 4 + 2)) & 15) << 3) | cl] = (short)u23;
        band[q * 4 + 3][(((cb ^ (q * 4 + 3)) & 15) << 3) | cl] = (short)(u23 >> 16);
      }
      LDS_FENCE();  // W writes must precede epilogue reads

      // ---- epilogue: prefetched x rows * W from band; lane owns f=2*lane,+1 ----
#pragma unroll
      for (int r = 0; r < 16; ++r) {
        unsigned pw;
        __builtin_memcpy(&pw, &band[r][(((cb2 ^ r) & 15) << 3) | cl2], 4);  // may-alias read
        o0 = fmaf(xpre[r][0], __builtin_bit_cast(float, pw << 16), o0);
        o1 = fmaf(xpre[r][1], __builtin_bit_cast(float, pw & 0xFFFF0000u), o1);
      }
      LDS_FENCE();  // epilogue reads must precede next half's H writes
    }

    __builtin_nontemporal_store(floatx2{o0, o1}, (floatx2*)(out + atom * FD + lane * 2));
  }
}

extern "C" void kernel_launch(void* const* d_in, const int* in_sizes, int n_in,
                              void* d_out, int out_size, void* d_ws, size_t ws_size,
                              hipStream_t stream) {
  const float* x   = (const float*)d_in[0];
  const float* rbf = (const float*)d_in[1];
  const int*   nbr = (const int*)d_in[2];
  const float* w1  = (const float*)d_in[3];
  const float* b1  = (const float*)d_in[4];
  const float* w2  = (const float*)d_in[5];
  const float* b2  = (const float*)d_in[6];
  float* out = (float*)d_out;

  // 80 KB LDS -> 2 blocks/CU. 500 blocks x 5 tiles each: exact, all co-resident.
  cfconv_kernel<<<dim3(500), dim3(512), 0, stream>>>(x, rbf, nbr, w1, b1, w2, b2, out);
}

// Round 7
// 288.984 us; speedup vs baseline: 1.4495x; 1.4495x over previous
//
#include <hip/hip_runtime.h>
#include <hip/hip_bf16.h>
#include <math.h>

// CFConv: out[a][f] = sum_n x[nbr[a][n]][f] * W[a][n][f]
//   W = (softplus(rbf @ w1 + b1)) @ w2 + b2
// N=20000 atoms, NB=32 neighbors, F=128, RBF=64.
//
// R7 = R6 minus the xpre prefetch (it spilled: WRITE_SIZE 10->298MB, dur
// 114->233us; a register prefetch that lands in scratch is a de-optimization).
// Keeps R6's scale-folded softplus: w1,b1 pre-scaled by log2e, w2 by ln2, so
// softplus(h) = log2(1+exp2(acc)) -- v_exp_f32 + v_add + v_log_f32.
// Structure = R5: 80 KB LDS (2 blocks/CU, 16 waves/CU), 8 waves/block, one
// atom per wave in two 16-row halves; swizzled wave-private LDS band stages
// H then W; epilogue does coalesced 512B x-row reads in-loop (lane owns
// f=2*lane, 2*lane+1); LDS_FENCE ordering guards the in-wave LDS reuse.

#define NB     32
#define FD     128
#define RD     64
#define WAVES  8
#define NTILES 2500   // 20000 / 8

#define LOG2E 1.4426950408889634f
#define LN2   0.6931471805599453f

typedef short  short8  __attribute__((ext_vector_type(8)));
typedef float  floatx4 __attribute__((ext_vector_type(4)));
typedef float  floatx2 __attribute__((ext_vector_type(2)));

#define LDS_FENCE() asm volatile("" ::: "memory")  // compiler-only ordering, no instr

static __device__ __forceinline__ unsigned pk2(float a, float b) {
  // packed fp32->bf16 RNE (v_cvt_pk_bf16_f32 on gfx950); low 16 = a
  __hip_bfloat162 h = __float22bfloat162_rn(float2{a, b});
  unsigned u;
  __builtin_memcpy(&u, &h, sizeof(u));
  return u;
}

// log2-domain softplus: log2e folded into GEMM1 operands, ln2 into w2.
static __device__ __forceinline__ float sp2(float acc) {
  return __builtin_amdgcn_logf(1.0f + __builtin_amdgcn_exp2f(acc));
}

__global__ __launch_bounds__(512, 4)  // 4 waves/EU = 2 blocks/CU (<=128 regs/wave)
void cfconv_kernel(const float* __restrict__ x,
                   const float* __restrict__ rbf,
                   const int*   __restrict__ nbr,
                   const float* __restrict__ w1,
                   const float* __restrict__ b1,
                   const float* __restrict__ w2,
                   const float* __restrict__ b2,
                   float* __restrict__ out) {
  // B-fragment layout: frag[kt*8+nt][lane][j] = B[kt*32 + (lane>>4)*8 + j][nt*16 + (lane&15)]
  __shared__ __align__(16) short w1f[16][64][8];        // 16 KB
  __shared__ __align__(16) short w2f[32][64][8];        // 32 KB
  // per-wave 16-row x 128-col bf16 staging (H, then W); 16B-block XOR swizzle:
  // element (row, col) lives at band[row][ ((col>>3 ^ row)&15)*8 + (col&7) ]
  __shared__ __align__(16) short hbuf[WAVES * 16][128]; // 32 KB -> total exactly 80 KB

  const int tid  = threadIdx.x;
  const int lane = tid & 63;
  const int wv   = tid >> 6;
  const int q    = lane >> 4;   // k-quad (A/B) or row-quad (C)
  const int ln   = lane & 15;   // m (A/C row) or n (B/C col) inside a 16-tile

  // ---- prepack weights (with scale folding) -> bf16 B-frags in LDS ----
  for (int i = tid; i < RD * FD; i += 512) {
    int k = i >> 7, n = i & 127, kk = k & 31;
    w1f[(k >> 5) * 8 + (n >> 4)][(kk >> 3) * 16 + (n & 15)][kk & 7] =
        (short)pk2(w1[i] * LOG2E, 0.f);
  }
  for (int i = tid; i < FD * FD; i += 512) {
    int k = i >> 7, n = i & 127, kk = k & 31;
    w2f[(k >> 5) * 8 + (n >> 4)][(kk >> 3) * 16 + (n & 15)][kk & 7] =
        (short)pk2(w2[i] * LN2, 0.f);
  }
  float b1v[8], b2v[8];
#pragma unroll
  for (int nt = 0; nt < 8; ++nt) {
    b1v[nt] = b1[nt * 16 + ln] * LOG2E;
    b2v[nt] = b2[nt * 16 + ln];
  }
  __syncthreads();  // the only barrier; hbuf use below is wave-private

  short (*band)[128] = &hbuf[wv * 16];
  const int cb2 = (lane * 2) >> 3;   // epilogue col-block for f = {2*lane, 2*lane+1}
  const int cl2 = (lane * 2) & 7;

  for (int tile = blockIdx.x; tile < NTILES; tile += gridDim.x) {
    const int atom = tile * WAVES + wv;
    const int prow = atom * NB;
    const int* nbp = nbr + prow;

    float o0 = 0.f, o1 = 0.f;

#pragma unroll
    for (int mt = 0; mt < 2; ++mt) {
      // ---- rbf A-frags for this 16-row half (nontemporal: streamed once) ----
      const float* src = rbf + (prow + mt * 16 + ln) * RD + q * 8;
      short8 afrag[2];
#pragma unroll
      for (int kt = 0; kt < 2; ++kt) {
        floatx4 lo = __builtin_nontemporal_load((const floatx4*)(src + kt * 32));
        floatx4 hi = __builtin_nontemporal_load((const floatx4*)(src + kt * 32 + 4));
        union { short8 s8; unsigned u[4]; } f;
        f.u[0] = pk2(lo[0], lo[1]);
        f.u[1] = pk2(lo[2], lo[3]);
        f.u[2] = pk2(hi[0], hi[1]);
        f.u[3] = pk2(hi[2], hi[3]);
        afrag[kt] = f.s8;
      }

      // ---- GEMM1: acc = (rbf @ w1 + b1) * log2e (scales folded), K=64 ----
      floatx4 acc[8];
#pragma unroll
      for (int nt = 0; nt < 8; ++nt) acc[nt] = floatx4{0.f, 0.f, 0.f, 0.f};
#pragma unroll
      for (int kt = 0; kt < 2; ++kt)
#pragma unroll
        for (int nt = 0; nt < 8; ++nt) {
          short8 bfrag = *(const short8*)&w1f[kt * 8 + nt][lane][0];
          acc[nt] = __builtin_amdgcn_mfma_f32_16x16x32_bf16(
              afrag[kt], bfrag, acc[nt], 0, 0, 0);
        }

      // ---- H' = log2(1+2^acc) -> bf16 -> swizzled band (C-layout) ----
#pragma unroll
      for (int nt = 0; nt < 8; ++nt) {
        const int c  = nt * 16 + ln;
        const int cb = c >> 3, cl = c & 7;
        unsigned u01 = pk2(sp2(acc[nt][0] + b1v[nt]), sp2(acc[nt][1] + b1v[nt]));
        unsigned u23 = pk2(sp2(acc[nt][2] + b1v[nt]), sp2(acc[nt][3] + b1v[nt]));
        band[q * 4 + 0][(((cb ^ (q * 4 + 0)) & 15) << 3) | cl] = (short)u01;
        band[q * 4 + 1][(((cb ^ (q * 4 + 1)) & 15) << 3) | cl] = (short)(u01 >> 16);
        band[q * 4 + 2][(((cb ^ (q * 4 + 2)) & 15) << 3) | cl] = (short)u23;
        band[q * 4 + 3][(((cb ^ (q * 4 + 3)) & 15) << 3) | cl] = (short)(u23 >> 16);
      }
      LDS_FENCE();  // H writes must precede hfrag reads in program order

      // ---- H A-frags from band: row=ln, cols kt*32+q*8..+7 (b128, swizzled) ----
      short8 hfrag[4];
#pragma unroll
      for (int kt = 0; kt < 4; ++kt) {
        const int pb = ((kt * 4 + q) ^ ln) & 15;
        hfrag[kt] = *(const short8*)&band[ln][pb << 3];
      }
      LDS_FENCE();  // hfrag reads must precede W overwrite

      // ---- GEMM2: W = H' @ (ln2*w2) + b2, K=128 (reuse acc) ----
#pragma unroll
      for (int nt = 0; nt < 8; ++nt) acc[nt] = floatx4{0.f, 0.f, 0.f, 0.f};
#pragma unroll
      for (int kt = 0; kt < 4; ++kt)
#pragma unroll
        for (int nt = 0; nt < 8; ++nt) {
          short8 bfrag = *(const short8*)&w2f[kt * 8 + nt][lane][0];
          acc[nt] = __builtin_amdgcn_mfma_f32_16x16x32_bf16(
              hfrag[kt], bfrag, acc[nt], 0, 0, 0);
        }

      // ---- W (bf16) back into the same band ----
#pragma unroll
      for (int nt = 0; nt < 8; ++nt) {
        const int c  = nt * 16 + ln;
        const int cb = c >> 3, cl = c & 7;
        unsigned u01 = pk2(acc[nt][0] + b2v[nt], acc[nt][1] + b2v[nt]);
        unsigned u23 = pk2(acc[nt][2] + b2v[nt], acc[nt][3] + b2v[nt]);
        band[q * 4 + 0][(((cb ^ (q * 4 + 0)) & 15) << 3) | cl] = (short)u01;
        band[q * 4 + 1][(((cb ^ (q * 4 + 1)) & 15) << 3) | cl] = (short)(u01 >> 16);
        band[q * 4 + 2][(((cb ^ (q * 4 + 2)) & 15) << 3) | cl] = (short)u23;
        band[q * 4 + 3][(((cb ^ (q * 4 + 3)) & 15) << 3) | cl] = (short)(u23 >> 16);
      }
      LDS_FENCE();  // W writes must precede epilogue reads

      // ---- epilogue: 16 rows, coalesced 512B x-row reads; lane owns f=2*lane,+1 ----
#pragma unroll 4
      for (int r = 0; r < 16; ++r) {
        const int j = nbp[mt * 16 + r];   // wave-uniform -> s_load
        floatx2 xv = *(const floatx2*)(x + j * FD + lane * 2);
        unsigned pw;
        __builtin_memcpy(&pw, &band[r][(((cb2 ^ r) & 15) << 3) | cl2], 4);  // may-alias read
        o0 = fmaf(xv[0], __builtin_bit_cast(float, pw << 16), o0);
        o1 = fmaf(xv[1], __builtin_bit_cast(float, pw & 0xFFFF0000u), o1);
      }
      LDS_FENCE();  // epilogue reads must precede next half's H writes
    }

    __builtin_nontemporal_store(floatx2{o0, o1}, (floatx2*)(out + atom * FD + lane * 2));
  }
}

extern "C" void kernel_launch(void* const* d_in, const int* in_sizes, int n_in,
                              void* d_out, int out_size, void* d_ws, size_t ws_size,
                              hipStream_t stream) {
  const float* x   = (const float*)d_in[0];
  const float* rbf = (const float*)d_in[1];
  const int*   nbr = (const int*)d_in[2];
  const float* w1  = (const float*)d_in[3];
  const float* b1  = (const float*)d_in[4];
  const float* w2  = (const float*)d_in[5];
  const float* b2  = (const float*)d_in[6];
  float* out = (float*)d_out;

  // 80 KB LDS -> 2 blocks/CU. 500 blocks x 5 tiles each: exact, all co-resident.
  cfconv_kernel<<<dim3(500), dim3(512), 0, stream>>>(x, rbf, nbr, w1, b1, w2, b2, out);
}